// Round 1
// 242.076 us; speedup vs baseline: 1.0238x; 1.0238x over previous
//
#include <hip/hip_runtime.h>

// Grad3D: out = |dx|+|dy|+|dz|, central differences, zero padding.
// fp32, (4,1,192,224,192) contiguous.
//
// R4: flat latency-optimized form.
// R3's rolling z-march was collapsed by the compiler: VGPR_Count=48 cannot
// hold the declared 12-float4 rolling state, so the "prefetch" loads were
// sunk to just-in-time, leaving every iteration latency-exposed
// (2.6 TB/s, VALUBusy 11%, Occupancy 39%). Here each thread computes 2
// z-planes of one float4 column with 12 fully INDEPENDENT loads issued as
// one batch (single vmcnt wait), no loop-carried dependence, then two
// nontemporal stores (write stream never re-read; keep input LLC-resident).
// Extra z-plane re-reads vs R3 are L2/LLC-absorbed — traffic was near-ideal
// already; parallelism was the deficit.

constexpr int W = 192, H = 224, D = 192, B = 4;
constexpr int W4     = W / 4;        // 48 float4 per row
constexpr int PLANE4 = W4 * H;       // 10752
constexpr int BY     = 4;            // rows per block (threadIdx.y)
constexpr int CH     = 2;            // z planes per thread
constexpr int ZC     = D / CH;       // 96
constexpr int YT     = H / BY;       // 56
constexpr int GRID   = B * ZC * YT;  // 21504  (= 84 blocks/CU exactly)
constexpr int PERX   = GRID / 8;     // 2688 blocks per XCD

typedef float f32x4 __attribute__((ext_vector_type(4)));

__global__ __launch_bounds__(192) void grad3d_kernel(
    const float* __restrict__ in, float* __restrict__ out) {
    // XCD-contiguous swizzle: HW round-robins bid across XCDs (bid%8);
    // remap so each XCD owns a contiguous spatial slab of 2688 blocks.
    int bid = blockIdx.x;
    int sid = (bid & 7) * PERX + (bid >> 3);
    const int yt = sid % YT; sid /= YT;
    const int zc = sid % ZC; sid /= ZC;
    const int b  = sid;

    const int xv = threadIdx.x;            // 0..47 (float4 within row)
    const int r  = yt * BY + threadIdx.y;  // row 0..223
    const int z0 = zc * CH;                // even plane

    const f32x4* __restrict__ in4 = (const f32x4*)in;
    f32x4* __restrict__ out4 = (f32x4*)out;
    const f32x4 zf = {0.f, 0.f, 0.f, 0.f};

    const bool has_l  = (xv > 0);
    const bool has_r  = (xv < W4 - 1);
    const bool has_ym = (r > 0);
    const bool has_yp = (r < H - 1);

    const int i0 = (b * D + z0) * PLANE4 + r * W4 + xv;  // plane z0
    const int i1 = i0 + PLANE4;                          // plane z0+1

    // ---- 8 vector + 4 scalar loads, all independent ----
    f32x4 czm = (z0 > 0)     ? in4[i0 - PLANE4] : zf;  // z0-1
    f32x4 c0  =                in4[i0];                // z0
    f32x4 c1  =                in4[i1];                // z0+1
    f32x4 czp = (z0 + 2 < D) ? in4[i1 + PLANE4] : zf;  // z0+2
    f32x4 ym0 = has_ym ? in4[i0 - W4] : zf;
    f32x4 yp0 = has_yp ? in4[i0 + W4] : zf;
    f32x4 ym1 = has_ym ? in4[i1 - W4] : zf;
    f32x4 yp1 = has_yp ? in4[i1 + W4] : zf;
    float l0  = has_l ? in[i0 * 4 - 1] : 0.f;
    float r0e = has_r ? in[i0 * 4 + 4] : 0.f;
    float l1  = has_l ? in[i1 * 4 - 1] : 0.f;
    float r1e = has_r ? in[i1 * 4 + 4] : 0.f;

    // ---- plane z0: dz = (c1 - czm)/2 ----
    f32x4 o0, o1;
    o0.x = fabsf((c0.y - l0  ) * .5f) + fabsf((yp0.x - ym0.x) * .5f) + fabsf((c1.x - czm.x) * .5f);
    o0.y = fabsf((c0.z - c0.x) * .5f) + fabsf((yp0.y - ym0.y) * .5f) + fabsf((c1.y - czm.y) * .5f);
    o0.z = fabsf((c0.w - c0.y) * .5f) + fabsf((yp0.z - ym0.z) * .5f) + fabsf((c1.z - czm.z) * .5f);
    o0.w = fabsf((r0e  - c0.z) * .5f) + fabsf((yp0.w - ym0.w) * .5f) + fabsf((c1.w - czm.w) * .5f);
    // ---- plane z0+1: dz = (czp - c0)/2 ----
    o1.x = fabsf((c1.y - l1  ) * .5f) + fabsf((yp1.x - ym1.x) * .5f) + fabsf((czp.x - c0.x) * .5f);
    o1.y = fabsf((c1.z - c1.x) * .5f) + fabsf((yp1.y - ym1.y) * .5f) + fabsf((czp.y - c0.y) * .5f);
    o1.z = fabsf((c1.w - c1.y) * .5f) + fabsf((yp1.z - ym1.z) * .5f) + fabsf((czp.z - c0.z) * .5f);
    o1.w = fabsf((r1e  - c1.z) * .5f) + fabsf((yp1.w - ym1.w) * .5f) + fabsf((czp.w - c0.w) * .5f);

    __builtin_nontemporal_store(o0, out4 + i0);
    __builtin_nontemporal_store(o1, out4 + i1);
}

extern "C" void kernel_launch(void* const* d_in, const int* in_sizes, int n_in,
                              void* d_out, int out_size, void* d_ws, size_t ws_size,
                              hipStream_t stream) {
    const float* x = (const float*)d_in[0];
    float* out     = (float*)d_out;
    dim3 block(W4, BY);                  // (48,4) = 192 threads = 3 waves
    grad3d_kernel<<<GRID, block, 0, stream>>>(x, out);
}

// Round 2
// 237.333 us; speedup vs baseline: 1.0443x; 1.0200x over previous
//
#include <hip/hip_runtime.h>

// Grad3D: out = |dx|+|dy|+|dz|, central differences, zero padding.
// fp32, (4,1,192,224,192) contiguous.
//
// R5: R4 flat form + (a) anti-sink asm pin so all 12 loads issue as one
// batch (R4's VGPR=24 proved the compiler serialized them), and
// (b) x-neighbor edge scalars via __shfl instead of 64-line gathers
// (the 4 scalar gathers were 2/3 of all cache-line transactions).
// Only wave-seam lanes (0/63) do real single-lane fixup loads.

constexpr int W = 192, H = 224, D = 192, B = 4;
constexpr int W4     = W / 4;        // 48 float4 per row
constexpr int PLANE4 = W4 * H;       // 10752
constexpr int BY     = 4;            // rows per block (threadIdx.y)
constexpr int CH     = 2;            // z planes per thread
constexpr int ZC     = D / CH;       // 96
constexpr int YT     = H / BY;       // 56
constexpr int GRID   = B * ZC * YT;  // 21504  (= 84 blocks/CU exactly)
constexpr int PERX   = GRID / 8;     // 2688 blocks per XCD

typedef float f32x4 __attribute__((ext_vector_type(4)));

__global__ __launch_bounds__(192) void grad3d_kernel(
    const float* __restrict__ in, float* __restrict__ out) {
    // XCD-contiguous swizzle (bijective: GRID % 8 == 0).
    int bid = blockIdx.x;
    int sid = (bid & 7) * PERX + (bid >> 3);
    const int yt = sid % YT; sid /= YT;
    const int zc = sid % ZC; sid /= ZC;
    const int b  = sid;

    const int xv = threadIdx.x;            // 0..47 (float4 within row)
    const int r  = yt * BY + threadIdx.y;  // row 0..223
    const int z0 = zc * CH;                // even plane
    const int lane = (threadIdx.x + W4 * threadIdx.y) & 63;

    const f32x4* __restrict__ in4 = (const f32x4*)in;
    f32x4* __restrict__ out4 = (f32x4*)out;
    const f32x4 zf = {0.f, 0.f, 0.f, 0.f};

    const bool has_ym = (r > 0);
    const bool has_yp = (r < H - 1);

    const int i0 = (b * D + z0) * PLANE4 + r * W4 + xv;  // plane z0
    const int i1 = i0 + PLANE4;                          // plane z0+1

    // ---- 8 vector loads, all independent ----
    f32x4 czm = (z0 > 0)     ? in4[i0 - PLANE4] : zf;  // z0-1
    f32x4 c0  =                in4[i0];                // z0
    f32x4 c1  =                in4[i1];                // z0+1
    f32x4 czp = (z0 + 2 < D) ? in4[i1 + PLANE4] : zf;  // z0+2
    f32x4 ym0 = has_ym ? in4[i0 - W4] : zf;
    f32x4 yp0 = has_yp ? in4[i0 + W4] : zf;
    f32x4 ym1 = has_ym ? in4[i1 - W4] : zf;
    f32x4 yp1 = has_yp ? in4[i1 + W4] : zf;

    // ---- wave-seam edge scalars: only lanes 0/63 touch memory ----
    float e_l0 = 0.f, e_l1 = 0.f, e_r0 = 0.f, e_r1 = 0.f;
    if (lane == 0 && xv > 0)       { e_l0 = in[i0 * 4 - 1]; e_l1 = in[i1 * 4 - 1]; }
    if (lane == 63 && xv < W4 - 1) { e_r0 = in[i0 * 4 + 4]; e_r1 = in[i1 * 4 + 4]; }

    // Anti-sink pin: force all loaded values live here so the scheduler
    // cannot serialize the loads to minimize register pressure (R4: VGPR=24).
    asm volatile("" :: "v"(czm), "v"(c0), "v"(c1), "v"(czp),
                       "v"(ym0), "v"(yp0), "v"(ym1), "v"(yp1),
                       "v"(e_l0), "v"(e_l1), "v"(e_r0), "v"(e_r1));

    // ---- x-neighbors via cross-lane shuffle (same row = adjacent lane) ----
    float l0  = __shfl_up(c0.w, 1);
    float l1  = __shfl_up(c1.w, 1);
    float r0e = __shfl_down(c0.x, 1);
    float r1e = __shfl_down(c1.x, 1);
    if (lane == 0)  { l0 = e_l0;  l1 = e_l1; }   // seam fixup (0 if xv==0)
    if (lane == 63) { r0e = e_r0; r1e = e_r1; }
    if (xv == 0)      { l0 = 0.f;  l1 = 0.f; }   // true x boundary
    if (xv == W4 - 1) { r0e = 0.f; r1e = 0.f; }

    // ---- plane z0: dz = (c1 - czm)/2 ----
    f32x4 o0, o1;
    o0.x = fabsf((c0.y - l0  ) * .5f) + fabsf((yp0.x - ym0.x) * .5f) + fabsf((c1.x - czm.x) * .5f);
    o0.y = fabsf((c0.z - c0.x) * .5f) + fabsf((yp0.y - ym0.y) * .5f) + fabsf((c1.y - czm.y) * .5f);
    o0.z = fabsf((c0.w - c0.y) * .5f) + fabsf((yp0.z - ym0.z) * .5f) + fabsf((c1.z - czm.z) * .5f);
    o0.w = fabsf((r0e  - c0.z) * .5f) + fabsf((yp0.w - ym0.w) * .5f) + fabsf((c1.w - czm.w) * .5f);
    // ---- plane z0+1: dz = (czp - c0)/2 ----
    o1.x = fabsf((c1.y - l1  ) * .5f) + fabsf((yp1.x - ym1.x) * .5f) + fabsf((czp.x - c0.x) * .5f);
    o1.y = fabsf((c1.z - c1.x) * .5f) + fabsf((yp1.y - ym1.y) * .5f) + fabsf((czp.y - c0.y) * .5f);
    o1.z = fabsf((c1.w - c1.y) * .5f) + fabsf((yp1.z - ym1.z) * .5f) + fabsf((czp.z - c0.z) * .5f);
    o1.w = fabsf((r1e  - c1.z) * .5f) + fabsf((yp1.w - ym1.w) * .5f) + fabsf((czp.w - c0.w) * .5f);

    __builtin_nontemporal_store(o0, out4 + i0);
    __builtin_nontemporal_store(o1, out4 + i1);
}

extern "C" void kernel_launch(void* const* d_in, const int* in_sizes, int n_in,
                              void* d_out, int out_size, void* d_ws, size_t ws_size,
                              hipStream_t stream) {
    const float* x = (const float*)d_in[0];
    float* out     = (float*)d_out;
    dim3 block(W4, BY);                  // (48,4) = 192 threads = 3 waves
    grad3d_kernel<<<GRID, block, 0, stream>>>(x, out);
}

// Round 3
// 233.196 us; speedup vs baseline: 1.0628x; 1.0177x over previous
//
#include <hip/hip_runtime.h>

// Grad3D: out = |dx|+|dy|+|dz|, central differences, zero padding.
// fp32, (4,1,192,224,192) contiguous.
//
// R6: inline-asm batched loads. R4/R5 proved (VGPR_Count=24, BW stuck at
// 2.3 TB/s) that hipcc rewrites any source-level "batch of 8 loads" into
// load-pair -> wait -> accumulate clusters to minimize register pressure
// (the |dx|+|dy|+|dz| sum lets it consume loads immediately). Each thread
// then eats ~4 serial memory round-trips. Here the 8 plane/row loads are
// ONE asm block: 8x global_load_dwordx4 + single s_waitcnt vmcnt(0),
// so 8 KB/wave is guaranteed in flight. Boundaries: clamped (always
// in-bounds) addresses + post-load selects instead of predicated loads.
// x-neighbors via __shfl + 2-seam-lane fixup loads (R5, verified).

constexpr int W = 192, H = 224, D = 192, B = 4;
constexpr int W4     = W / 4;        // 48 float4 per row
constexpr int PLANE4 = W4 * H;       // 10752
constexpr int BY     = 4;            // rows per block (threadIdx.y)
constexpr int CH     = 2;            // z planes per thread
constexpr int ZC     = D / CH;       // 96
constexpr int YT     = H / BY;       // 56
constexpr int GRID   = B * ZC * YT;  // 21504  (= 84 blocks/CU exactly)
constexpr int PERX   = GRID / 8;     // 2688 blocks per XCD

typedef float f32x4 __attribute__((ext_vector_type(4)));

__global__ __launch_bounds__(192, 4) void grad3d_kernel(
    const float* __restrict__ in, float* __restrict__ out) {
    // XCD-contiguous swizzle (bijective: GRID % 8 == 0).
    int bid = blockIdx.x;
    int sid = (bid & 7) * PERX + (bid >> 3);
    const int yt = sid % YT; sid /= YT;
    const int zc = sid % ZC; sid /= ZC;
    const int b  = sid;

    const int xv = threadIdx.x;            // 0..47 (float4 within row)
    const int r  = yt * BY + threadIdx.y;  // row 0..223
    const int z0 = zc * CH;                // even plane
    const int lane = (threadIdx.x + W4 * threadIdx.y) & 63;

    f32x4* __restrict__ out4 = (f32x4*)out;
    const f32x4 zf = {0.f, 0.f, 0.f, 0.f};

    const bool has_ym = (r > 0);
    const bool has_yp = (r < H - 1);
    const bool vzm    = (z0 > 0);
    const bool vzp    = (z0 + 2 < D);

    const int i0 = (b * D + z0) * PLANE4 + r * W4 + xv;  // plane z0 (float4 idx)
    const int i1 = i0 + PLANE4;                          // plane z0+1

    // Clamped, always-in-bounds addresses (selects applied post-load).
    const float* p_c0  = in + 4 * i0;
    const float* p_c1  = in + 4 * i1;
    const float* p_czm = in + 4 * (i0 - (vzm    ? PLANE4 : 0));
    const float* p_czp = in + 4 * (i1 + (vzp    ? PLANE4 : 0));
    const float* p_ym0 = in + 4 * (i0 - (has_ym ? W4 : 0));
    const float* p_yp0 = in + 4 * (i0 + (has_yp ? W4 : 0));
    const float* p_ym1 = in + 4 * (i1 - (has_ym ? W4 : 0));
    const float* p_yp1 = in + 4 * (i1 + (has_yp ? W4 : 0));

    // ---- wave-seam edge scalars: only lanes 0/63 touch memory ----
    float e_l0 = 0.f, e_l1 = 0.f, e_r0 = 0.f, e_r1 = 0.f;
    if (lane == 0 && xv > 0)       { e_l0 = in[i0 * 4 - 1]; e_l1 = in[i1 * 4 - 1]; }
    if (lane == 63 && xv < W4 - 1) { e_r0 = in[i0 * 4 + 4]; e_r1 = in[i1 * 4 + 4]; }
    __builtin_amdgcn_sched_barrier(0);   // seam loads stay before the batch

    // ---- the batch: 8 independent 16B loads, ONE waitcnt ----
    f32x4 czm, c0, c1, czp, ym0, yp0, ym1, yp1;
    asm volatile(
        "global_load_dwordx4 %0, %8, off\n\t"
        "global_load_dwordx4 %1, %9, off\n\t"
        "global_load_dwordx4 %2, %10, off\n\t"
        "global_load_dwordx4 %3, %11, off\n\t"
        "global_load_dwordx4 %4, %12, off\n\t"
        "global_load_dwordx4 %5, %13, off\n\t"
        "global_load_dwordx4 %6, %14, off\n\t"
        "global_load_dwordx4 %7, %15, off\n\t"
        "s_waitcnt vmcnt(0)"
        : "=&v"(czm), "=&v"(c0), "=&v"(c1), "=&v"(czp),
          "=&v"(ym0), "=&v"(yp0), "=&v"(ym1), "=&v"(yp1)
        : "v"(p_czm), "v"(p_c0), "v"(p_c1), "v"(p_czp),
          "v"(p_ym0), "v"(p_yp0), "v"(p_ym1), "v"(p_yp1)
        : "memory");
    __builtin_amdgcn_sched_barrier(0);

    // ---- boundary selects (z: block-uniform scalar branch; y: cndmask) ----
    if (!vzm) czm = zf;
    if (!vzp) czp = zf;
    ym0 = has_ym ? ym0 : zf;
    ym1 = has_ym ? ym1 : zf;
    yp0 = has_yp ? yp0 : zf;
    yp1 = has_yp ? yp1 : zf;

    // ---- x-neighbors via cross-lane shuffle (same row = adjacent lane) ----
    float l0  = __shfl_up(c0.w, 1);
    float l1  = __shfl_up(c1.w, 1);
    float r0e = __shfl_down(c0.x, 1);
    float r1e = __shfl_down(c1.x, 1);
    if (lane == 0)  { l0 = e_l0;  l1 = e_l1; }   // seam fixup (0 if xv==0)
    if (lane == 63) { r0e = e_r0; r1e = e_r1; }
    if (xv == 0)      { l0 = 0.f;  l1 = 0.f; }   // true x boundary
    if (xv == W4 - 1) { r0e = 0.f; r1e = 0.f; }

    // ---- plane z0: dz = (c1 - czm)/2 ----
    f32x4 o0, o1;
    o0.x = fabsf((c0.y - l0  ) * .5f) + fabsf((yp0.x - ym0.x) * .5f) + fabsf((c1.x - czm.x) * .5f);
    o0.y = fabsf((c0.z - c0.x) * .5f) + fabsf((yp0.y - ym0.y) * .5f) + fabsf((c1.y - czm.y) * .5f);
    o0.z = fabsf((c0.w - c0.y) * .5f) + fabsf((yp0.z - ym0.z) * .5f) + fabsf((c1.z - czm.z) * .5f);
    o0.w = fabsf((r0e  - c0.z) * .5f) + fabsf((yp0.w - ym0.w) * .5f) + fabsf((c1.w - czm.w) * .5f);
    // ---- plane z0+1: dz = (czp - c0)/2 ----
    o1.x = fabsf((c1.y - l1  ) * .5f) + fabsf((yp1.x - ym1.x) * .5f) + fabsf((czp.x - c0.x) * .5f);
    o1.y = fabsf((c1.z - c1.x) * .5f) + fabsf((yp1.y - ym1.y) * .5f) + fabsf((czp.y - c0.y) * .5f);
    o1.z = fabsf((c1.w - c1.y) * .5f) + fabsf((yp1.z - ym1.z) * .5f) + fabsf((czp.z - c0.z) * .5f);
    o1.w = fabsf((r1e  - c1.z) * .5f) + fabsf((yp1.w - ym1.w) * .5f) + fabsf((czp.w - c0.w) * .5f);

    __builtin_nontemporal_store(o0, out4 + i0);
    __builtin_nontemporal_store(o1, out4 + i1);
}

extern "C" void kernel_launch(void* const* d_in, const int* in_sizes, int n_in,
                              void* d_out, int out_size, void* d_ws, size_t ws_size,
                              hipStream_t stream) {
    const float* x = (const float*)d_in[0];
    float* out     = (float*)d_out;
    dim3 block(W4, BY);                  // (48,4) = 192 threads = 3 waves
    grad3d_kernel<<<GRID, block, 0, stream>>>(x, out);
}

// Round 4
// 231.808 us; speedup vs baseline: 1.0692x; 1.0060x over previous
//
#include <hip/hip_runtime.h>

// Grad3D: out = |dx|+|dy|+|dz|, central differences, zero padding.
// fp32, (4,1,192,224,192) contiguous.
//
// R7: LDS-tiled. R6 falsified latency-serialization (forced 8-load asm
// batch: 2.32->2.42 TB/s only). Remaining theory: per-CU vector-memory
// transaction throughput — all prior versions load 8 float4 per 2 output
// float4 (4x logical read amplification, ~1.06 GB through L1s, ~81K
// lines/CU). Here each block stages a (6+2)x(8+2)x192 tile ONCE into LDS
// (61.4 KB) via global_load_lds width=16, then reads neighbors from LDS.
// Read amplification 4x -> 1.67x (halo only); ~3x fewer L1 transactions.
// All LDS access patterns are linear (full-W rows contiguous) ->
// conflict-free. Boundary halos pre-zeroed; staging lanes masked off them.

constexpr int W = 192, H = 224, D = 192, B = 4;
constexpr int W4   = W / 4;          // 48 float4 per row
constexpr int ZT   = 6, YT = 8;      // output tile: 6 planes x 8 rows x 192
constexpr int ZP   = ZT + 2;         // 8 LDS planes (z halo)
constexpr int YP   = YT + 2;         // 10 LDS rows per plane (y halo)
constexpr int ROWB = W * 4;          // 768 B per row
constexpr int PLB  = YP * ROWB;      // 7680 B per LDS plane
constexpr int LDSB = ZP * PLB;       // 61440 B total
constexpr int NZ   = D / ZT;         // 32
constexpr int NY   = H / YT;         // 28
constexpr int GRID = B * NZ * NY;    // 3584  (% 8 == 0)
constexpr int PERX = GRID / 8;       // 448 blocks per XCD

typedef float f32x4 __attribute__((ext_vector_type(4)));
typedef __attribute__((address_space(3))) unsigned int       lds_u32;
typedef __attribute__((address_space(1))) const unsigned int gbl_u32;

__global__ __launch_bounds__(384) void grad3d_kernel(
    const float* __restrict__ in, float* __restrict__ out) {
    __shared__ float s[LDSB / 4];    // [8 planes][10 rows][192 floats]

    // XCD-contiguous swizzle (bijective: GRID % 8 == 0).
    int bid = blockIdx.x;
    int sid = (bid & 7) * PERX + (bid >> 3);
    const int yt = sid % NY; sid /= NY;
    const int zc = sid % NZ; sid /= NZ;
    const int b  = sid;

    const int xv   = threadIdx.x;          // 0..47
    const int y    = threadIdx.y;          // 0..7
    const int flat = y * W4 + xv;          // 0..383
    const int wv   = flat >> 6;            // wave 0..5
    const int lane = flat & 63;

    const int y0 = yt * YT;
    const int z0 = zc * ZT;
    const bool ybot = (y0 == 0);
    const bool ytop = (y0 + YT == H);

    f32x4* s4 = (f32x4*)s;
    const f32x4 zf = {0.f, 0.f, 0.f, 0.f};

    // ---- pre-zero halo regions that staging will skip (disjoint from
    // staged bytes -> single barrier suffices) ----
    if (z0 == 0)                                      // z=-1 plane -> zeros
        for (int i = flat; i < PLB / 16; i += 384) s4[i] = zf;
    if (z0 + ZT == D)                                 // z=D plane -> zeros
        for (int i = flat; i < PLB / 16; i += 384) s4[(LDSB - PLB) / 16 + i] = zf;
    if (ybot)                                         // row y=-1 of each plane
        s4[y * (PLB / 16) + xv] = zf;                 // (y as plane idx 0..7)
    if (ytop)                                         // row y=H of each plane
        s4[y * (PLB / 16) + (YP - 1) * W4 + xv] = zf;

    // ---- stage: 64 chunks (8 planes x 8 sub-chunks of <=1KB), round-robin
    // over the 6 waves. LDS dest = wave-uniform chunk base (+lane*16 by HW);
    // global source per-lane. OOB halo lanes exec-masked off. ----
    const char* inb = (const char*)in;
    for (int c = wv; c < 64; c += 6) {
        const int zz = c >> 3;                         // LDS plane 0..7
        const int j  = c & 7;                          // 1KB sub-chunk
        const int gz = z0 - 1 + zz;
        if (gz < 0 || gz >= D) continue;               // pre-zeroed plane
        const int p = (j << 10) + (lane << 4);         // byte within plane tile
        bool ok = (p < PLB);                           // tail chunk: lanes<32
        if (ybot && p < ROWB)       ok = false;        // y=-1 row (pre-zeroed)
        if (ytop && p >= PLB - ROWB) ok = false;       // y=H row (pre-zeroed)
        if (ok) {
            // rows y0-1 .. y0+8 of plane gz are one contiguous global chunk
            const char* g = inb + (size_t)((b * D + gz) * H + (y0 - 1)) * ROWB + p;
            unsigned int* l = (unsigned int*)((char*)s + zz * PLB + (j << 10));
            __builtin_amdgcn_global_load_lds((gbl_u32*)g, (lds_u32*)l, 16, 0, 0);
        }
    }

    __syncthreads();   // drains vmcnt before barrier (compiler-enforced)

    // ---- compute: 6 z-passes; all neighbors from LDS (linear, conflict-free)
    f32x4* out4 = (f32x4*)out;
    constexpr int rowf = W;        // 192 floats per LDS row
    constexpr int plf  = YP * W;   // 1920 floats per LDS plane
    int ci = (YP + (y + 1)) * rowf + 4 * xv;   // plane 1, row y+1, float idx
    size_t oi = ((size_t)(b * D + z0) * H + (y0 + y)) * W4 + xv;

#pragma unroll
    for (int z = 0; z < ZT; ++z) {
        f32x4 cc = *(const f32x4*)&s[ci];
        f32x4 ym = *(const f32x4*)&s[ci - rowf];
        f32x4 yp = *(const f32x4*)&s[ci + rowf];
        f32x4 zm = *(const f32x4*)&s[ci - plf];
        f32x4 zp = *(const f32x4*)&s[ci + plf];
        float l  = (xv > 0)      ? s[ci - 1] : 0.f;   // in-row scalar
        float r  = (xv < W4 - 1) ? s[ci + 4] : 0.f;

        f32x4 o;
        o.x = fabsf((cc.y - l   ) * .5f) + fabsf((yp.x - ym.x) * .5f) + fabsf((zp.x - zm.x) * .5f);
        o.y = fabsf((cc.z - cc.x) * .5f) + fabsf((yp.y - ym.y) * .5f) + fabsf((zp.y - zm.y) * .5f);
        o.z = fabsf((cc.w - cc.y) * .5f) + fabsf((yp.z - ym.z) * .5f) + fabsf((zp.z - zm.z) * .5f);
        o.w = fabsf((r    - cc.z) * .5f) + fabsf((yp.w - ym.w) * .5f) + fabsf((zp.w - zm.w) * .5f);
        __builtin_nontemporal_store(o, out4 + oi);

        ci += plf;
        oi += (size_t)H * W4;
    }
}

extern "C" void kernel_launch(void* const* d_in, const int* in_sizes, int n_in,
                              void* d_out, int out_size, void* d_ws, size_t ws_size,
                              hipStream_t stream) {
    const float* x = (const float*)d_in[0];
    float* out     = (float*)d_out;
    dim3 block(W4, YT);              // (48,8) = 384 threads = 6 waves
    grad3d_kernel<<<GRID, block, 0, stream>>>(x, out);
}

// Round 5
// 231.286 us; speedup vs baseline: 1.0716x; 1.0023x over previous
//
#include <hip/hip_runtime.h>

// Grad3D: out = |dx|+|dy|+|dz|, central differences, zero padding.
// fp32, (4,1,192,224,192) contiguous.
//
// R8: R7 with occupancy/de-phasing fix. Five structures all pinned at
// 2.3-2.6 TB/s regardless of MLP or transaction count -> theory: per-wave
// read-in-flight duty cycle (~40%) caps BW; R7 had only 2 blocks/CU
// (Occupancy 15%) so stage bursts and LDS-compute stretches could not
// overlap across blocks. Here: ZT=2 tile -> 30.7 KB LDS, launch_bounds
// (384,8) -> <=64 VGPR -> 5 blocks/CU (30 waves). Also: l/r x-neighbors
// via __shfl + 2 seam lanes instead of stride-16B scalar LDS reads
// (kills R7's 1.55M bank-conflict cycles).

constexpr int W = 192, H = 224, D = 192, B = 4;
constexpr int W4   = W / 4;          // 48 float4 per row
constexpr int ZT   = 2, YT = 8;      // output tile: 2 planes x 8 rows x 192
constexpr int ZP   = ZT + 2;         // 4 LDS planes (z halo)
constexpr int YP   = YT + 2;         // 10 LDS rows per plane (y halo)
constexpr int ROWB = W * 4;          // 768 B per row
constexpr int PLB  = YP * ROWB;      // 7680 B per LDS plane
constexpr int LDSB = ZP * PLB;       // 30720 B total
constexpr int NZ   = D / ZT;         // 96
constexpr int NY   = H / YT;         // 28
constexpr int GRID = B * NZ * NY;    // 10752  (% 8 == 0)
constexpr int PERX = GRID / 8;       // 1344 blocks per XCD

typedef float f32x4 __attribute__((ext_vector_type(4)));
typedef __attribute__((address_space(3))) unsigned int       lds_u32;
typedef __attribute__((address_space(1))) const unsigned int gbl_u32;

__global__ __launch_bounds__(384, 8) void grad3d_kernel(
    const float* __restrict__ in, float* __restrict__ out) {
    __shared__ float s[LDSB / 4];    // [4 planes][10 rows][192 floats]

    // XCD-contiguous swizzle (bijective: GRID % 8 == 0).
    int bid = blockIdx.x;
    int sid = (bid & 7) * PERX + (bid >> 3);
    const int yt = sid % NY; sid /= NY;
    const int zc = sid % NZ; sid /= NZ;
    const int b  = sid;

    const int xv   = threadIdx.x;          // 0..47
    const int y    = threadIdx.y;          // 0..7
    const int flat = y * W4 + xv;          // 0..383
    const int wv   = flat >> 6;            // wave 0..5
    const int lane = flat & 63;

    const int y0 = yt * YT;
    const int z0 = zc * ZT;
    const bool ybot = (y0 == 0);
    const bool ytop = (y0 + YT == H);

    f32x4* s4 = (f32x4*)s;
    const f32x4 zf = {0.f, 0.f, 0.f, 0.f};

    // ---- pre-zero halo regions staging will skip (disjoint from staged
    // bytes -> the single barrier suffices) ----
    if (z0 == 0)                                      // z=-1 plane -> zeros
        for (int i = flat; i < PLB / 16; i += 384) s4[i] = zf;
    if (z0 + ZT == D)                                 // z=D plane -> zeros
        for (int i = flat; i < PLB / 16; i += 384) s4[(LDSB - PLB) / 16 + i] = zf;
    if (ybot && y < ZP)                               // row y=-1 of each plane
        s4[y * (PLB / 16) + xv] = zf;                 // (y as plane idx 0..3)
    if (ytop && y < ZP)                               // row y=H of each plane
        s4[y * (PLB / 16) + (YP - 1) * W4 + xv] = zf;

    // ---- stage: 32 chunks (4 planes x 8 sub-chunks of <=1KB), round-robin
    // over the 6 waves. LDS dest = wave-uniform chunk base (+lane*16 by HW);
    // global source per-lane. OOB halo lanes exec-masked off. ----
    const char* inb = (const char*)in;
    for (int c = wv; c < 32; c += 6) {
        const int zz = c >> 3;                         // LDS plane 0..3
        const int j  = c & 7;                          // 1KB sub-chunk
        const int gz = z0 - 1 + zz;
        if (gz < 0 || gz >= D) continue;               // pre-zeroed plane
        const int p = (j << 10) + (lane << 4);         // byte within plane tile
        bool ok = (p < PLB);                           // tail chunk: lanes<32
        if (ybot && p < ROWB)        ok = false;       // y=-1 row (pre-zeroed)
        if (ytop && p >= PLB - ROWB) ok = false;       // y=H row (pre-zeroed)
        if (ok) {
            // rows y0-1 .. y0+8 of plane gz are one contiguous global chunk
            const char* g = inb + (size_t)((b * D + gz) * H + (y0 - 1)) * ROWB + p;
            unsigned int* l = (unsigned int*)((char*)s + zz * PLB + (j << 10));
            __builtin_amdgcn_global_load_lds((gbl_u32*)g, (lds_u32*)l, 16, 0, 0);
        }
    }

    __syncthreads();   // drains vmcnt before barrier (compiler-enforced)

    // ---- compute: 2 z-passes; vector neighbors from LDS (conflict-free),
    // x-neighbors via cross-lane shuffle + 2 seam lanes ----
    f32x4* out4 = (f32x4*)out;
    constexpr int rowf = W;        // 192 floats per LDS row
    constexpr int plf  = YP * W;   // 1920 floats per LDS plane
    int ci = (YP + (y + 1)) * rowf + 4 * xv;   // plane 1, row y+1, float idx
    size_t oi = ((size_t)(b * D + z0) * H + (y0 + y)) * W4 + xv;

#pragma unroll
    for (int z = 0; z < ZT; ++z) {
        f32x4 cc = *(const f32x4*)&s[ci];
        f32x4 ym = *(const f32x4*)&s[ci - rowf];
        f32x4 yp = *(const f32x4*)&s[ci + rowf];
        f32x4 zm = *(const f32x4*)&s[ci - plf];
        f32x4 zp = *(const f32x4*)&s[ci + plf];

        float l = __shfl_up(cc.w, 1);
        float r = __shfl_down(cc.x, 1);
        if (lane == 0  && xv > 0)      l = s[ci - 1];   // wave-seam fixup
        if (lane == 63 && xv < W4 - 1) r = s[ci + 4];
        if (xv == 0)      l = 0.f;                      // true x boundary
        if (xv == W4 - 1) r = 0.f;

        f32x4 o;
        o.x = fabsf((cc.y - l   ) * .5f) + fabsf((yp.x - ym.x) * .5f) + fabsf((zp.x - zm.x) * .5f);
        o.y = fabsf((cc.z - cc.x) * .5f) + fabsf((yp.y - ym.y) * .5f) + fabsf((zp.y - zm.y) * .5f);
        o.z = fabsf((cc.w - cc.y) * .5f) + fabsf((yp.z - ym.z) * .5f) + fabsf((zp.z - zm.z) * .5f);
        o.w = fabsf((r    - cc.z) * .5f) + fabsf((yp.w - ym.w) * .5f) + fabsf((zp.w - zm.w) * .5f);
        __builtin_nontemporal_store(o, out4 + oi);

        ci += plf;
        oi += (size_t)H * W4;
    }
}

extern "C" void kernel_launch(void* const* d_in, const int* in_sizes, int n_in,
                              void* d_out, int out_size, void* d_ws, size_t ws_size,
                              hipStream_t stream) {
    const float* x = (const float*)d_in[0];
    float* out     = (float*)d_out;
    dim3 block(W4, YT);              // (48,8) = 384 threads = 6 waves
    grad3d_kernel<<<GRID, block, 0, stream>>>(x, out);
}